// Round 1
// baseline (107.137 us; speedup 1.0000x reference)
//
#include <hip/hip_runtime.h>

// out[b,c,h,w] = x[b,c,h,w] + pe(c,h)
//   pe(c,h) = sin(h / 10000^((c&~1)/C))  if c even
//           = cos(h / 10000^((c&~1)/C))  if c odd
// x: (16, 64, 256, 256) fp32, contiguous NCHW.

constexpr int B_ = 16, C_ = 64, H_ = 256, W_ = 256;
constexpr int N4 = (B_ * C_ * H_ * W_) / 4;  // 16,777,216 float4s

__global__ void PositionalEncoding_56805237457391_kernel(
    const float* __restrict__ x, float* __restrict__ out) {
    // log2(10000) / C  (C = 64)
    const float LOG2_10000_OVER_C = 13.287712379549449f / 64.0f;

    const int stride = gridDim.x * blockDim.x;
    for (int i = blockIdx.x * blockDim.x + threadIdx.x; i < N4; i += stride) {
        // float4 index -> (row = (b*C + c)*H + h), since W/4 = 64 float4s/row.
        const int row = i >> 6;          // i / (W/4)
        const int h   = row & (H_ - 1);  // row % 256
        const int c   = (row >> 8) & (C_ - 1);

        // freq = 10000^(-(c&~1)/C) = exp2(-(c&~1) * log2(10000)/C)
        const float e    = (float)(c & ~1) * LOG2_10000_OVER_C;
        const float freq = exp2f(-e);
        const float arg  = (float)h * freq;
        const float pe   = (c & 1) ? cosf(arg) : sinf(arg);

        float4 v = reinterpret_cast<const float4*>(x)[i];
        v.x += pe; v.y += pe; v.z += pe; v.w += pe;
        reinterpret_cast<float4*>(out)[i] = v;
    }
}

extern "C" void kernel_launch(void* const* d_in, const int* in_sizes, int n_in,
                              void* d_out, int out_size, void* d_ws, size_t ws_size,
                              hipStream_t stream) {
    const float* x = (const float*)d_in[0];
    float* out = (float*)d_out;

    const int block = 256;
    // Memory-bound: cap at ~8 blocks/CU * 256 CUs and grid-stride the rest.
    int grid = (N4 + block - 1) / block;
    if (grid > 2048) grid = 2048;

    PositionalEncoding_56805237457391_kernel<<<grid, block, 0, stream>>>(x, out);
}